// Round 1
// baseline (192.931 us; speedup 1.0000x reference)
//
#include <hip/hip_runtime.h>
#include <hip/hip_bf16.h>

// Shapes
#define BN   64
#define TN   1024
#define EN   512
#define AN   512
#define HN   512
#define G3H  1536

typedef __bf16 bf16x8 __attribute__((ext_vector_type(8)));
typedef __bf16 bf16x4 __attribute__((ext_vector_type(4)));
typedef float  f32x8  __attribute__((ext_vector_type(8)));
typedef float  f32x4  __attribute__((ext_vector_type(4)));
typedef unsigned int uint4v __attribute__((ext_vector_type(4)));

__device__ __forceinline__ float fast_tanh(float x) {
    float e = __expf(2.0f * x);
    return 1.0f - 2.0f / (e + 1.0f);
}
__device__ __forceinline__ float fast_sigmoid(float x) {
    return 1.0f / (1.0f + __expf(-x));
}

// ---------------------------------------------------------------------------
// prep: task-split by blockIdx.x
//   [0,64)      st_proj[b][n] = states[b,:] @ W_state          (fp32)
//   [64,72)     wencT[n][k] = bf16(W_enc[k][n])                (transpose+cvt)
//   [72,840)    wihbf = bf16(W_ih)        1536x1024
//   [840,1224)  whhbf = bf16(W_hh)        1536x512
//   [1224,1240) xbf[b][0..511] = bf16(inputs[b][:])
//   [1240,1256) stbf = bf16(states)
// ---------------------------------------------------------------------------
__global__ __launch_bounds__(256) void prep_kernel(
    const float* __restrict__ states, const float* __restrict__ W_enc,
    const float* __restrict__ W_state, const float* __restrict__ inputs,
    const float* __restrict__ W_ih, const float* __restrict__ W_hh,
    float* __restrict__ stp, __bf16* __restrict__ wencT,
    __bf16* __restrict__ xbf, __bf16* __restrict__ stbf,
    __bf16* __restrict__ wihbf, __bf16* __restrict__ whhbf)
{
    __shared__ float srow[512];
    int blk = blockIdx.x, tid = threadIdx.x;

    if (blk < 64) {
        int b = blk;
        srow[tid] = states[b * 512 + tid];
        srow[tid + 256] = states[b * 512 + tid + 256];
        __syncthreads();
        int n0 = tid, n1 = tid + 256;
        float a0 = 0.f, a1 = 0.f;
        for (int k = 0; k < 512; ++k) {
            float s = srow[k];
            a0 += s * W_state[k * 512 + n0];
            a1 += s * W_state[k * 512 + n1];
        }
        stp[b * 512 + n0] = a0;
        stp[b * 512 + n1] = a1;
    } else if (blk < 72) {
        int n = (blk - 64) * 64 + (tid & 63);
        int cseg = tid >> 6;
        for (int c = cseg * 16; c < cseg * 16 + 16; ++c) {
            f32x8 f;
            #pragma unroll
            for (int j = 0; j < 8; ++j) f[j] = W_enc[(c * 8 + j) * 512 + n];
            *(bf16x8*)(wencT + n * 512 + c * 8) = __builtin_convertvector(f, bf16x8);
        }
    } else if (blk < 840) {
        int base4 = (blk - 72) * 512 + tid * 2;
        #pragma unroll
        for (int j = 0; j < 2; ++j) {
            int i4 = base4 + j;
            f32x4 f = *(const f32x4*)(W_ih + i4 * 4);
            *(bf16x4*)(wihbf + i4 * 4) = __builtin_convertvector(f, bf16x4);
        }
    } else if (blk < 1224) {
        int base4 = (blk - 840) * 512 + tid * 2;
        #pragma unroll
        for (int j = 0; j < 2; ++j) {
            int i4 = base4 + j;
            f32x4 f = *(const f32x4*)(W_hh + i4 * 4);
            *(bf16x4*)(whhbf + i4 * 4) = __builtin_convertvector(f, bf16x4);
        }
    } else if (blk < 1240) {
        int base4 = (blk - 1224) * 512 + tid * 2;
        #pragma unroll
        for (int j = 0; j < 2; ++j) {
            int i4 = base4 + j;
            int e = i4 * 4;
            int b = e >> 9, c = e & 511;
            f32x4 f = *(const f32x4*)(inputs + e);
            *(bf16x4*)(xbf + b * 1024 + c) = __builtin_convertvector(f, bf16x4);
        }
    } else {
        int base4 = (blk - 1240) * 512 + tid * 2;
        #pragma unroll
        for (int j = 0; j < 2; ++j) {
            int i4 = base4 + j;
            int e = i4 * 4;
            f32x4 f = *(const f32x4*)(states + e);
            *(bf16x4*)(stbf + e) = __builtin_convertvector(f, bf16x4);
        }
    }
}

// ---------------------------------------------------------------------------
// score: per block = (b, 128-row t-block). Full N=512 looped in 4 chunks of
// 128; K=512 in 8 chunks of 64. MFMA 16x16x32 bf16, fused tanh + v-dot
// epilogue; only scores[b][t] leaves the kernel.
// 4 waves arranged 2x2 over the 128x128 (rows x cols) tile.
// ---------------------------------------------------------------------------
__global__ __launch_bounds__(256) void score_kernel(
    const float* __restrict__ enc, const __bf16* __restrict__ wencT,
    const float* __restrict__ stp, const float* __restrict__ v,
    float* __restrict__ scores)
{
    __shared__ __align__(16) __bf16 As[128 * 72];   // +8 pad: 2-way-only conflicts
    __shared__ __align__(16) __bf16 Bs[128 * 72];
    __shared__ float stv[128], vvl[128];
    __shared__ float sacc[2][128];

    int tid = threadIdx.x;
    int b = blockIdx.x >> 3, t0 = (blockIdx.x & 7) << 7;
    int lane = tid & 63, wid = tid >> 6;
    int wrow = wid >> 1, wcol = wid & 1;
    int l15 = lane & 15, g = lane >> 4;

    if (tid < 128) { sacc[0][tid] = 0.f; sacc[1][tid] = 0.f; }

    int ar = tid >> 1, ah = tid & 1;  // A staging: row, half-row(32 floats)
    const float* asrc = enc + ((b * 1024 + t0 + ar) * 512 + ah * 32);

    for (int nc = 0; nc < 4; ++nc) {
        __syncthreads();  // protect stv/vvl from previous epilogue readers
        if (tid < 128) {
            stv[tid] = stp[b * 512 + nc * 128 + tid];
            vvl[tid] = v[nc * 128 + tid];
        }
        f32x4 acc[4][4];
        #pragma unroll
        for (int i = 0; i < 4; ++i)
            #pragma unroll
            for (int j = 0; j < 4; ++j) acc[i][j] = (f32x4){0.f, 0.f, 0.f, 0.f};

        for (int kc = 0; kc < 8; ++kc) {
            int k0 = kc * 64;
            // stage A: fp32 -> bf16 (v_cvt_pk via convertvector)
            const float* ap = asrc + k0;
            #pragma unroll
            for (int q = 0; q < 4; ++q) {
                f32x8 f = *(const f32x8*)(ap + q * 8);
                *(bf16x8*)(As + ar * 72 + ah * 32 + q * 8) =
                    __builtin_convertvector(f, bf16x8);
            }
            // stage B: already bf16, straight 16B copies
            #pragma unroll
            for (int q = 0; q < 4; ++q) {
                int ch = tid * 4 + q;
                int row = ch >> 3, seg = ch & 7;
                uint4v u = *(const uint4v*)(wencT + ((nc * 128 + row) * 512 + k0 + seg * 8));
                *(uint4v*)(Bs + row * 72 + seg * 8) = u;
            }
            __syncthreads();
            #pragma unroll
            for (int kk = 0; kk < 2; ++kk) {
                bf16x8 af[4], bfr[4];
                #pragma unroll
                for (int m = 0; m < 4; ++m)
                    af[m] = *(const bf16x8*)(As + (wrow * 64 + m * 16 + l15) * 72 + kk * 32 + g * 8);
                #pragma unroll
                for (int n = 0; n < 4; ++n)
                    bfr[n] = *(const bf16x8*)(Bs + (wcol * 64 + n * 16 + l15) * 72 + kk * 32 + g * 8);
                #pragma unroll
                for (int m = 0; m < 4; ++m)
                    #pragma unroll
                    for (int n = 0; n < 4; ++n)
                        acc[m][n] = __builtin_amdgcn_mfma_f32_16x16x32_bf16(
                            af[m], bfr[n], acc[m][n], 0, 0, 0);
            }
            __syncthreads();
        }
        // fused epilogue: rowpart += v[n] * tanh(proj + st_proj[n])
        float rp[16];
        #pragma unroll
        for (int i = 0; i < 16; ++i) rp[i] = 0.f;
        #pragma unroll
        for (int m = 0; m < 4; ++m)
            #pragma unroll
            for (int n = 0; n < 4; ++n) {
                int col = wcol * 64 + n * 16 + l15;
                float sv = stv[col], vw = vvl[col];
                #pragma unroll
                for (int r = 0; r < 4; ++r)
                    rp[m * 4 + r] += vw * fast_tanh(acc[m][n][r] + sv);
            }
        // reduce over the 16 col-lanes (same g-group)
        #pragma unroll
        for (int i = 0; i < 16; ++i) {
            rp[i] += __shfl_xor(rp[i], 1);
            rp[i] += __shfl_xor(rp[i], 2);
            rp[i] += __shfl_xor(rp[i], 4);
            rp[i] += __shfl_xor(rp[i], 8);
        }
        if (l15 == 0) {
            #pragma unroll
            for (int m = 0; m < 4; ++m)
                #pragma unroll
                for (int r = 0; r < 4; ++r)
                    sacc[wcol][wrow * 64 + m * 16 + g * 4 + r] += rp[m * 4 + r];
        }
    }
    __syncthreads();
    if (tid < 128) scores[b * 1024 + t0 + tid] = sacc[0][tid] + sacc[1][tid];
}

// ---------------------------------------------------------------------------
// ctx: per block = (b, 128-col e-chunk). Softmax over scores[b,:] (redundant
// per chunk, cheap), then context = sum_t w[t]*enc[b,t,cols]; writes bf16
// context half of x.
// ---------------------------------------------------------------------------
__global__ __launch_bounds__(256) void ctx_kernel(
    const float* __restrict__ scores, const float* __restrict__ enc,
    __bf16* __restrict__ xbf)
{
    __shared__ float wsm[1024];
    __shared__ float red[512];
    __shared__ float tmp[8];
    int tid = threadIdx.x, lane = tid & 63, w = tid >> 6;
    int b = blockIdx.x >> 2, c0 = (blockIdx.x & 3) * 128;

    f32x4 s = *(const f32x4*)(scores + b * 1024 + tid * 4);
    float m = fmaxf(fmaxf(s[0], s[1]), fmaxf(s[2], s[3]));
    #pragma unroll
    for (int off = 32; off >= 1; off >>= 1) m = fmaxf(m, __shfl_xor(m, off));
    if (lane == 0) tmp[w] = m;
    __syncthreads();
    float M = fmaxf(fmaxf(tmp[0], tmp[1]), fmaxf(tmp[2], tmp[3]));
    float e0 = __expf(s[0] - M), e1 = __expf(s[1] - M);
    float e2 = __expf(s[2] - M), e3 = __expf(s[3] - M);
    wsm[tid * 4 + 0] = e0; wsm[tid * 4 + 1] = e1;
    wsm[tid * 4 + 2] = e2; wsm[tid * 4 + 3] = e3;
    float sum = e0 + e1 + e2 + e3;
    #pragma unroll
    for (int off = 32; off >= 1; off >>= 1) sum += __shfl_xor(sum, off);
    if (lane == 0) tmp[4 + w] = sum;
    __syncthreads();
    float S = tmp[4] + tmp[5] + tmp[6] + tmp[7];

    // context: wave w covers t in [w*256, w*256+256); lane owns 2 cols
    const float* ep = enc + ((b * 1024 + w * 256) * 512 + c0 + lane * 2);
    float ax = 0.f, ay = 0.f;
    #pragma unroll 4
    for (int t = 0; t < 256; ++t) {
        float wt = wsm[w * 256 + t];
        float2 ev = *(const float2*)(ep + t * 512);
        ax += wt * ev.x;
        ay += wt * ev.y;
    }
    red[w * 128 + lane * 2] = ax;
    red[w * 128 + lane * 2 + 1] = ay;
    __syncthreads();
    if (tid < 128) {
        float c = (red[tid] + red[128 + tid] + red[256 + tid] + red[384 + tid]) / S;
        xbf[b * 1024 + 512 + c0 + tid] = (__bf16)c;
    }
}

// ---------------------------------------------------------------------------
// gru_gemm: blocks [0,12) -> gi = x @ W_ih^T (K=1024); [12,24) -> gh =
// states @ W_hh^T (K=512). M=64, N-chunk=128 per block. 4 waves x 32 cols.
// ---------------------------------------------------------------------------
__global__ __launch_bounds__(256) void gru_gemm(
    const __bf16* __restrict__ xbf, const __bf16* __restrict__ stbf,
    const __bf16* __restrict__ wihbf, const __bf16* __restrict__ whhbf,
    const float* __restrict__ b_ih, const float* __restrict__ b_hh,
    float* __restrict__ gi, float* __restrict__ gh)
{
    __shared__ __align__(16) __bf16 As[64 * 72];
    __shared__ __align__(16) __bf16 Bs[128 * 72];
    int blk = blockIdx.x, tid = threadIdx.x;
    bool is_gh = blk >= 12;
    int n0 = (is_gh ? blk - 12 : blk) * 128;
    int K = is_gh ? 512 : 1024;
    const __bf16* Aptr = is_gh ? stbf : xbf;
    const __bf16* Bptr = is_gh ? whhbf : wihbf;
    const float* bias = is_gh ? b_hh : b_ih;
    float* outp = is_gh ? gh : gi;

    int lane = tid & 63, wid = tid >> 6, l15 = lane & 15, g = lane >> 4;
    f32x4 acc[4][2];
    #pragma unroll
    for (int i = 0; i < 4; ++i)
        #pragma unroll
        for (int j = 0; j < 2; ++j) acc[i][j] = (f32x4){0.f, 0.f, 0.f, 0.f};

    int nkc = K >> 6;
    for (int kc = 0; kc < nkc; ++kc) {
        int k0 = kc * 64;
        #pragma unroll
        for (int q = 0; q < 2; ++q) {
            int ch = tid * 2 + q, row = ch >> 3, seg = ch & 7;
            uint4v u = *(const uint4v*)(Aptr + row * K + k0 + seg * 8);
            *(uint4v*)(As + row * 72 + seg * 8) = u;
        }
        #pragma unroll
        for (int q = 0; q < 4; ++q) {
            int ch = tid * 4 + q, row = ch >> 3, seg = ch & 7;
            uint4v u = *(const uint4v*)(Bptr + (n0 + row) * K + k0 + seg * 8);
            *(uint4v*)(Bs + row * 72 + seg * 8) = u;
        }
        __syncthreads();
        #pragma unroll
        for (int kk = 0; kk < 2; ++kk) {
            bf16x8 af[4], bfr[2];
            #pragma unroll
            for (int m = 0; m < 4; ++m)
                af[m] = *(const bf16x8*)(As + (m * 16 + l15) * 72 + kk * 32 + g * 8);
            #pragma unroll
            for (int n = 0; n < 2; ++n)
                bfr[n] = *(const bf16x8*)(Bs + (wid * 32 + n * 16 + l15) * 72 + kk * 32 + g * 8);
            #pragma unroll
            for (int m = 0; m < 4; ++m)
                #pragma unroll
                for (int n = 0; n < 2; ++n)
                    acc[m][n] = __builtin_amdgcn_mfma_f32_16x16x32_bf16(
                        af[m], bfr[n], acc[m][n], 0, 0, 0);
        }
        __syncthreads();
    }
    #pragma unroll
    for (int m = 0; m < 4; ++m)
        #pragma unroll
        for (int n = 0; n < 2; ++n) {
            int col = n0 + wid * 32 + n * 16 + l15;
            float bb = bias[col];
            #pragma unroll
            for (int r = 0; r < 4; ++r) {
                int brow = m * 16 + g * 4 + r;
                outp[brow * 1536 + col] = acc[m][n][r] + bb;
            }
        }
}

// ---------------------------------------------------------------------------
// gates: elementwise GRU combine
// ---------------------------------------------------------------------------
__global__ __launch_bounds__(256) void gru_gates(
    const float* __restrict__ gi, const float* __restrict__ gh,
    const float* __restrict__ states, float* __restrict__ out)
{
    int i = blockIdx.x * 256 + threadIdx.x;  // 32768 total
    int b = i >> 9, j = i & 511;
    const float* gib = gi + b * 1536;
    const float* ghb = gh + b * 1536;
    float r = fast_sigmoid(gib[j] + ghb[j]);
    float z = fast_sigmoid(gib[512 + j] + ghb[512 + j]);
    float n = fast_tanh(gib[1024 + j] + r * ghb[1024 + j]);
    out[i] = (1.f - z) * n + z * states[i];
}

// ---------------------------------------------------------------------------
extern "C" void kernel_launch(void* const* d_in, const int* in_sizes, int n_in,
                              void* d_out, int out_size, void* d_ws, size_t ws_size,
                              hipStream_t stream)
{
    const float* inputs  = (const float*)d_in[0];
    const float* states  = (const float*)d_in[1];
    const float* encoded = (const float*)d_in[2];
    const float* W_enc   = (const float*)d_in[3];
    const float* W_state = (const float*)d_in[4];
    const float* v       = (const float*)d_in[5];
    const float* W_ih    = (const float*)d_in[6];
    const float* W_hh    = (const float*)d_in[7];
    const float* b_ih    = (const float*)d_in[8];
    const float* b_hh    = (const float*)d_in[9];
    float* out = (float*)d_out;
    char* ws = (char*)d_ws;

    float*  stp    = (float*)(ws + 0);         //  64*512*4   = 131072
    __bf16* wencT  = (__bf16*)(ws + 131072);   // 512*512*2   = 524288
    float*  scores = (float*)(ws + 655360);    //  64*1024*4  = 262144
    __bf16* xbf    = (__bf16*)(ws + 917504);   //  64*1024*2  = 131072
    __bf16* stbf   = (__bf16*)(ws + 1048576);  //  64*512*2   = 65536
    __bf16* wihbf  = (__bf16*)(ws + 1114112);  // 1536*1024*2 = 3145728
    __bf16* whhbf  = (__bf16*)(ws + 4259840);  // 1536*512*2  = 1572864
    float*  gi     = (float*)(ws + 5832704);   //  64*1536*4  = 393216
    float*  gh     = (float*)(ws + 6225920);   //  64*1536*4  = 393216

    prep_kernel<<<1256, 256, 0, stream>>>(states, W_enc, W_state, inputs, W_ih, W_hh,
                                          stp, wencT, xbf, stbf, wihbf, whhbf);
    score_kernel<<<512, 256, 0, stream>>>(encoded, wencT, stp, v, scores);
    ctx_kernel<<<256, 256, 0, stream>>>(scores, encoded, xbf);
    gru_gemm<<<24, 256, 0, stream>>>(xbf, stbf, wihbf, whhbf, b_ih, b_hh, gi, gh);
    gru_gates<<<128, 256, 0, stream>>>(gi, gh, states, out);
}

// Round 2
// 140.782 us; speedup vs baseline: 1.3704x; 1.3704x over previous
//
#include <hip/hip_runtime.h>
#include <hip/hip_bf16.h>

// Shapes
#define BN   64
#define TN   1024
#define EN   512
#define AN   512
#define HN   512
#define G3H  1536

typedef __bf16 bf16x8 __attribute__((ext_vector_type(8)));
typedef __bf16 bf16x4 __attribute__((ext_vector_type(4)));
typedef float  f32x8  __attribute__((ext_vector_type(8)));
typedef float  f32x4  __attribute__((ext_vector_type(4)));
typedef unsigned int uint4v __attribute__((ext_vector_type(4)));

__device__ __forceinline__ float fast_tanh(float x) {
    float e = __expf(2.0f * x);
    return 1.0f - 2.0f / (e + 1.0f);
}
__device__ __forceinline__ float fast_sigmoid(float x) {
    return 1.0f / (1.0f + __expf(-x));
}

// ---------------------------------------------------------------------------
// prep (unchanged): task-split by blockIdx.x
// ---------------------------------------------------------------------------
__global__ __launch_bounds__(256) void prep_kernel(
    const float* __restrict__ states, const float* __restrict__ W_enc,
    const float* __restrict__ W_state, const float* __restrict__ inputs,
    const float* __restrict__ W_ih, const float* __restrict__ W_hh,
    float* __restrict__ stp, __bf16* __restrict__ wencT,
    __bf16* __restrict__ xbf, __bf16* __restrict__ stbf,
    __bf16* __restrict__ wihbf, __bf16* __restrict__ whhbf)
{
    __shared__ float srow[512];
    int blk = blockIdx.x, tid = threadIdx.x;

    if (blk < 64) {
        int b = blk;
        srow[tid] = states[b * 512 + tid];
        srow[tid + 256] = states[b * 512 + tid + 256];
        __syncthreads();
        int n0 = tid, n1 = tid + 256;
        float a0 = 0.f, a1 = 0.f;
        for (int k = 0; k < 512; ++k) {
            float s = srow[k];
            a0 += s * W_state[k * 512 + n0];
            a1 += s * W_state[k * 512 + n1];
        }
        stp[b * 512 + n0] = a0;
        stp[b * 512 + n1] = a1;
    } else if (blk < 72) {
        int n = (blk - 64) * 64 + (tid & 63);
        int cseg = tid >> 6;
        for (int c = cseg * 16; c < cseg * 16 + 16; ++c) {
            f32x8 f;
            #pragma unroll
            for (int j = 0; j < 8; ++j) f[j] = W_enc[(c * 8 + j) * 512 + n];
            *(bf16x8*)(wencT + n * 512 + c * 8) = __builtin_convertvector(f, bf16x8);
        }
    } else if (blk < 840) {
        int base4 = (blk - 72) * 512 + tid * 2;
        #pragma unroll
        for (int j = 0; j < 2; ++j) {
            int i4 = base4 + j;
            f32x4 f = *(const f32x4*)(W_ih + i4 * 4);
            *(bf16x4*)(wihbf + i4 * 4) = __builtin_convertvector(f, bf16x4);
        }
    } else if (blk < 1224) {
        int base4 = (blk - 840) * 512 + tid * 2;
        #pragma unroll
        for (int j = 0; j < 2; ++j) {
            int i4 = base4 + j;
            f32x4 f = *(const f32x4*)(W_hh + i4 * 4);
            *(bf16x4*)(whhbf + i4 * 4) = __builtin_convertvector(f, bf16x4);
        }
    } else if (blk < 1240) {
        int base4 = (blk - 1224) * 512 + tid * 2;
        #pragma unroll
        for (int j = 0; j < 2; ++j) {
            int i4 = base4 + j;
            int e = i4 * 4;
            int b = e >> 9, c = e & 511;
            f32x4 f = *(const f32x4*)(inputs + e);
            *(bf16x4*)(xbf + b * 1024 + c) = __builtin_convertvector(f, bf16x4);
        }
    } else {
        int base4 = (blk - 1240) * 512 + tid * 2;
        #pragma unroll
        for (int j = 0; j < 2; ++j) {
            int i4 = base4 + j;
            int e = i4 * 4;
            f32x4 f = *(const f32x4*)(states + e);
            *(bf16x4*)(stbf + e) = __builtin_convertvector(f, bf16x4);
        }
    }
}

// ---------------------------------------------------------------------------
// score v2: block = (b, 128-row t-block), 512 threads / 8 waves (2 wrow x 4
// wcol, wave tile 64x64). A tile (128x512) staged to LDS as bf16 ONCE,
// interleaved with nc=0 compute (kc-pair granularity). B chunk [256][40]
// re-staged per kc with register prefetch. Raw s_barrier + lgkmcnt(0) so
// prefetch loads stay in flight across barriers.
// ---------------------------------------------------------------------------
__global__ __launch_bounds__(512) void score_kernel(
    const float* __restrict__ enc, const __bf16* __restrict__ wencT,
    const float* __restrict__ stp, const float* __restrict__ v,
    float* __restrict__ scores)
{
    extern __shared__ char smem[];
    __bf16* As  = (__bf16*)smem;                       // [128][520] = 133120 B
    __bf16* Bs  = (__bf16*)(smem + 133120);            // [256][40]  =  20480 B
    float*  stv = (float*)(smem + 133120 + 20480);     // [256]
    float*  vvl = stv + 256;                           // [256]
    float*  sacc = vvl + 256;                          // [4][128]

    int tid = threadIdx.x;
    int b = blockIdx.x >> 3, t0 = (blockIdx.x & 7) << 7;
    int lane = tid & 63;
    int wid = tid >> 6;
    int wrow = wid >> 2, wcol = wid & 3;
    int l15 = lane & 15, g = lane >> 4;

    if (tid < 128) {
        sacc[tid] = 0.f; sacc[128 + tid] = 0.f;
        sacc[256 + tid] = 0.f; sacc[384 + tid] = 0.f;
    }

    // staging maps (2 chunks of 16B per thread per stage)
    int rA[2], sA[2], rB[2], sB[2];
    #pragma unroll
    for (int q = 0; q < 2; ++q) {
        int chA = tid * 2 + q; rA[q] = chA >> 3; sA[q] = chA & 7;   // 128 rows x 8 seg (pair window 128B)
        int chB = tid * 2 + q; rB[q] = chB >> 2; sB[q] = chB & 3;   // 256 rows x 4 seg (64B)
    }

    const float* aBase = enc + (size_t)((b * 1024 + t0)) * 512;

    // prologue: prefetch A pair 0 and B(nc0,kc0)
    f32x8 aN[2];
    uint4v bN[2];
    #pragma unroll
    for (int q = 0; q < 2; ++q)
        aN[q] = *(const f32x8*)(aBase + rA[q] * 512 + sA[q] * 8);
    #pragma unroll
    for (int q = 0; q < 2; ++q)
        bN[q] = *(const uint4v*)(wencT + rB[q] * 512 + sB[q] * 8);

    for (int nc = 0; nc < 2; ++nc) {
        __syncthreads();
        if (tid < 256) {
            stv[tid] = stp[b * 512 + nc * 256 + tid];
            vvl[tid] = v[nc * 256 + tid];
        }
        f32x4 acc[4][4];
        #pragma unroll
        for (int i = 0; i < 4; ++i)
            #pragma unroll
            for (int j = 0; j < 4; ++j) acc[i][j] = (f32x4){0.f, 0.f, 0.f, 0.f};

        for (int kc = 0; kc < 16; ++kc) {
            bool stA = (nc == 0) && ((kc & 1) == 0);
            if (stA) {
                int kcp = kc >> 1;
                #pragma unroll
                for (int q = 0; q < 2; ++q)
                    *(bf16x8*)(As + rA[q] * 520 + kcp * 64 + sA[q] * 8) =
                        __builtin_convertvector(aN[q], bf16x8);
                if (kc < 14) {
                    #pragma unroll
                    for (int q = 0; q < 2; ++q)
                        aN[q] = *(const f32x8*)(aBase + rA[q] * 512 + (kcp + 1) * 64 + sA[q] * 8);
                }
            }
            // write current B chunk
            #pragma unroll
            for (int q = 0; q < 2; ++q)
                *(uint4v*)(Bs + rB[q] * 40 + sB[q] * 8) = bN[q];
            // prefetch next B chunk
            int nnc = (kc == 15) ? nc + 1 : nc;
            int nkc = (kc == 15) ? 0 : kc + 1;
            if (nnc < 2) {
                #pragma unroll
                for (int q = 0; q < 2; ++q)
                    bN[q] = *(const uint4v*)(wencT + (nnc * 256 + rB[q]) * 512 + nkc * 32 + sB[q] * 8);
            }
            asm volatile("s_waitcnt lgkmcnt(0)" ::: "memory");
            __builtin_amdgcn_s_barrier();

            bf16x8 af[4], bfr[4];
            #pragma unroll
            for (int m = 0; m < 4; ++m)
                af[m] = *(const bf16x8*)(As + (wrow * 64 + m * 16 + l15) * 520 + kc * 32 + g * 8);
            #pragma unroll
            for (int n = 0; n < 4; ++n)
                bfr[n] = *(const bf16x8*)(Bs + (wcol * 64 + n * 16 + l15) * 40 + g * 8);
            #pragma unroll
            for (int m = 0; m < 4; ++m)
                #pragma unroll
                for (int n = 0; n < 4; ++n)
                    acc[m][n] = __builtin_amdgcn_mfma_f32_16x16x32_bf16(
                        af[m], bfr[n], acc[m][n], 0, 0, 0);
            __builtin_amdgcn_s_barrier();
        }
        // fused epilogue: rowpart += v[col] * tanh(proj + st_proj[col])
        float rp[16];
        #pragma unroll
        for (int i = 0; i < 16; ++i) rp[i] = 0.f;
        #pragma unroll
        for (int m = 0; m < 4; ++m)
            #pragma unroll
            for (int n = 0; n < 4; ++n) {
                int col = wcol * 64 + n * 16 + l15;
                float sv = stv[col], vw = vvl[col];
                #pragma unroll
                for (int r = 0; r < 4; ++r)
                    rp[m * 4 + r] += vw * fast_tanh(acc[m][n][r] + sv);
            }
        #pragma unroll
        for (int i = 0; i < 16; ++i) {
            rp[i] += __shfl_xor(rp[i], 1);
            rp[i] += __shfl_xor(rp[i], 2);
            rp[i] += __shfl_xor(rp[i], 4);
            rp[i] += __shfl_xor(rp[i], 8);
        }
        if (l15 == 0) {
            #pragma unroll
            for (int m = 0; m < 4; ++m)
                #pragma unroll
                for (int r = 0; r < 4; ++r)
                    sacc[wcol * 128 + wrow * 64 + m * 16 + g * 4 + r] += rp[m * 4 + r];
        }
    }
    __syncthreads();
    if (tid < 128)
        scores[b * 1024 + t0 + tid] =
            sacc[tid] + sacc[128 + tid] + sacc[256 + tid] + sacc[384 + tid];
}

// ---------------------------------------------------------------------------
// ctx (unchanged): softmax + context, writes bf16 context half of x.
// ---------------------------------------------------------------------------
__global__ __launch_bounds__(256) void ctx_kernel(
    const float* __restrict__ scores, const float* __restrict__ enc,
    __bf16* __restrict__ xbf)
{
    __shared__ float wsm[1024];
    __shared__ float red[512];
    __shared__ float tmp[8];
    int tid = threadIdx.x, lane = tid & 63, w = tid >> 6;
    int b = blockIdx.x >> 2, c0 = (blockIdx.x & 3) * 128;

    f32x4 s = *(const f32x4*)(scores + b * 1024 + tid * 4);
    float m = fmaxf(fmaxf(s[0], s[1]), fmaxf(s[2], s[3]));
    #pragma unroll
    for (int off = 32; off >= 1; off >>= 1) m = fmaxf(m, __shfl_xor(m, off));
    if (lane == 0) tmp[w] = m;
    __syncthreads();
    float M = fmaxf(fmaxf(tmp[0], tmp[1]), fmaxf(tmp[2], tmp[3]));
    float e0 = __expf(s[0] - M), e1 = __expf(s[1] - M);
    float e2 = __expf(s[2] - M), e3 = __expf(s[3] - M);
    wsm[tid * 4 + 0] = e0; wsm[tid * 4 + 1] = e1;
    wsm[tid * 4 + 2] = e2; wsm[tid * 4 + 3] = e3;
    float sum = e0 + e1 + e2 + e3;
    #pragma unroll
    for (int off = 32; off >= 1; off >>= 1) sum += __shfl_xor(sum, off);
    if (lane == 0) tmp[4 + w] = sum;
    __syncthreads();
    float S = tmp[4] + tmp[5] + tmp[6] + tmp[7];

    const float* ep = enc + ((b * 1024 + w * 256) * 512 + c0 + lane * 2);
    float ax = 0.f, ay = 0.f;
    #pragma unroll 4
    for (int t = 0; t < 256; ++t) {
        float wt = wsm[w * 256 + t];
        float2 ev = *(const float2*)(ep + t * 512);
        ax += wt * ev.x;
        ay += wt * ev.y;
    }
    red[w * 128 + lane * 2] = ax;
    red[w * 128 + lane * 2 + 1] = ay;
    __syncthreads();
    if (tid < 128) {
        float c = (red[tid] + red[128 + tid] + red[256 + tid] + red[384 + tid]) / S;
        xbf[b * 1024 + 512 + c0 + tid] = (__bf16)c;
    }
}

// ---------------------------------------------------------------------------
// gru_gemm (unchanged)
// ---------------------------------------------------------------------------
__global__ __launch_bounds__(256) void gru_gemm(
    const __bf16* __restrict__ xbf, const __bf16* __restrict__ stbf,
    const __bf16* __restrict__ wihbf, const __bf16* __restrict__ whhbf,
    const float* __restrict__ b_ih, const float* __restrict__ b_hh,
    float* __restrict__ gi, float* __restrict__ gh)
{
    __shared__ __align__(16) __bf16 As[64 * 72];
    __shared__ __align__(16) __bf16 Bs[128 * 72];
    int blk = blockIdx.x, tid = threadIdx.x;
    bool is_gh = blk >= 12;
    int n0 = (is_gh ? blk - 12 : blk) * 128;
    int K = is_gh ? 512 : 1024;
    const __bf16* Aptr = is_gh ? stbf : xbf;
    const __bf16* Bptr = is_gh ? whhbf : wihbf;
    const float* bias = is_gh ? b_hh : b_ih;
    float* outp = is_gh ? gh : gi;

    int lane = tid & 63, wid = tid >> 6, l15 = lane & 15, g = lane >> 4;
    f32x4 acc[4][2];
    #pragma unroll
    for (int i = 0; i < 4; ++i)
        #pragma unroll
        for (int j = 0; j < 2; ++j) acc[i][j] = (f32x4){0.f, 0.f, 0.f, 0.f};

    int nkc = K >> 6;
    for (int kc = 0; kc < nkc; ++kc) {
        int k0 = kc * 64;
        #pragma unroll
        for (int q = 0; q < 2; ++q) {
            int ch = tid * 2 + q, row = ch >> 3, seg = ch & 7;
            uint4v u = *(const uint4v*)(Aptr + row * K + k0 + seg * 8);
            *(uint4v*)(As + row * 72 + seg * 8) = u;
        }
        #pragma unroll
        for (int q = 0; q < 4; ++q) {
            int ch = tid * 4 + q, row = ch >> 3, seg = ch & 7;
            uint4v u = *(const uint4v*)(Bptr + (n0 + row) * K + k0 + seg * 8);
            *(uint4v*)(Bs + row * 72 + seg * 8) = u;
        }
        __syncthreads();
        #pragma unroll
        for (int kk = 0; kk < 2; ++kk) {
            bf16x8 af[4], bfr[2];
            #pragma unroll
            for (int m = 0; m < 4; ++m)
                af[m] = *(const bf16x8*)(As + (m * 16 + l15) * 72 + kk * 32 + g * 8);
            #pragma unroll
            for (int n = 0; n < 2; ++n)
                bfr[n] = *(const bf16x8*)(Bs + (wid * 32 + n * 16 + l15) * 72 + kk * 32 + g * 8);
            #pragma unroll
            for (int m = 0; m < 4; ++m)
                #pragma unroll
                for (int n = 0; n < 2; ++n)
                    acc[m][n] = __builtin_amdgcn_mfma_f32_16x16x32_bf16(
                        af[m], bfr[n], acc[m][n], 0, 0, 0);
        }
        __syncthreads();
    }
    #pragma unroll
    for (int m = 0; m < 4; ++m)
        #pragma unroll
        for (int n = 0; n < 2; ++n) {
            int col = n0 + wid * 32 + n * 16 + l15;
            float bb = bias[col];
            #pragma unroll
            for (int r = 0; r < 4; ++r) {
                int brow = m * 16 + g * 4 + r;
                outp[brow * 1536 + col] = acc[m][n][r] + bb;
            }
        }
}

// ---------------------------------------------------------------------------
// gates (unchanged)
// ---------------------------------------------------------------------------
__global__ __launch_bounds__(256) void gru_gates(
    const float* __restrict__ gi, const float* __restrict__ gh,
    const float* __restrict__ states, float* __restrict__ out)
{
    int i = blockIdx.x * 256 + threadIdx.x;  // 32768 total
    int b = i >> 9, j = i & 511;
    const float* gib = gi + b * 1536;
    const float* ghb = gh + b * 1536;
    float r = fast_sigmoid(gib[j] + ghb[j]);
    float z = fast_sigmoid(gib[512 + j] + ghb[512 + j]);
    float n = fast_tanh(gib[1024 + j] + r * ghb[1024 + j]);
    out[i] = (1.f - z) * n + z * states[i];
}

// ---------------------------------------------------------------------------
extern "C" void kernel_launch(void* const* d_in, const int* in_sizes, int n_in,
                              void* d_out, int out_size, void* d_ws, size_t ws_size,
                              hipStream_t stream)
{
    const float* inputs  = (const float*)d_in[0];
    const float* states  = (const float*)d_in[1];
    const float* encoded = (const float*)d_in[2];
    const float* W_enc   = (const float*)d_in[3];
    const float* W_state = (const float*)d_in[4];
    const float* v       = (const float*)d_in[5];
    const float* W_ih    = (const float*)d_in[6];
    const float* W_hh    = (const float*)d_in[7];
    const float* b_ih    = (const float*)d_in[8];
    const float* b_hh    = (const float*)d_in[9];
    float* out = (float*)d_out;
    char* ws = (char*)d_ws;

    float*  stp    = (float*)(ws + 0);         //  64*512*4   = 131072
    __bf16* wencT  = (__bf16*)(ws + 131072);   // 512*512*2   = 524288
    float*  scores = (float*)(ws + 655360);    //  64*1024*4  = 262144
    __bf16* xbf    = (__bf16*)(ws + 917504);   //  64*1024*2  = 131072
    __bf16* stbf   = (__bf16*)(ws + 1048576);  //  64*512*2   = 65536
    __bf16* wihbf  = (__bf16*)(ws + 1114112);  // 1536*1024*2 = 3145728
    __bf16* whhbf  = (__bf16*)(ws + 4259840);  // 1536*512*2  = 1572864
    float*  gi     = (float*)(ws + 5832704);   //  64*1536*4  = 393216
    float*  gh     = (float*)(ws + 6225920);   //  64*1536*4  = 393216

    prep_kernel<<<1256, 256, 0, stream>>>(states, W_enc, W_state, inputs, W_ih, W_hh,
                                          stp, wencT, xbf, stbf, wihbf, whhbf);
    score_kernel<<<512, 512, 157696, stream>>>(encoded, wencT, stp, v, scores);
    ctx_kernel<<<256, 256, 0, stream>>>(scores, encoded, xbf);
    gru_gemm<<<24, 256, 0, stream>>>(xbf, stbf, wihbf, whhbf, b_ih, b_hh, gi, gh);
    gru_gates<<<128, 256, 0, stream>>>(gi, gh, states, out);
}

// Round 4
// 124.780 us; speedup vs baseline: 1.5462x; 1.1282x over previous
//
#include <hip/hip_runtime.h>
#include <hip/hip_bf16.h>

// Shapes
#define BN   64
#define TN   1024
#define EN   512
#define AN   512
#define HN   512
#define G3H  1536

typedef __bf16 bf16x8 __attribute__((ext_vector_type(8)));
typedef __bf16 bf16x4 __attribute__((ext_vector_type(4)));
typedef float  f32x8  __attribute__((ext_vector_type(8)));
typedef float  f32x4  __attribute__((ext_vector_type(4)));
typedef unsigned int uint4v __attribute__((ext_vector_type(4)));

__device__ __forceinline__ float fast_tanh(float x) {
    float e = __expf(2.0f * x);
    return 1.0f - 2.0f / (e + 1.0f);
}
__device__ __forceinline__ float fast_sigmoid(float x) {
    return 1.0f / (1.0f + __expf(-x));
}

// ---------------------------------------------------------------------------
// prep: task-split by blockIdx.x
//   [0,64)      st_proj fp32 GEMV
//   [64,72)     wencT transpose+cvt
//   [72,840)    wihbf cvt
//   [840,1224)  whhbf cvt
//   [1224,1240) xbf (inputs half)
//   [1240,1256) stbf
//   [1256,1320) zero scores (for score_kernel atomicAdd)
// ---------------------------------------------------------------------------
__global__ __launch_bounds__(256) void prep_kernel(
    const float* __restrict__ states, const float* __restrict__ W_enc,
    const float* __restrict__ W_state, const float* __restrict__ inputs,
    const float* __restrict__ W_ih, const float* __restrict__ W_hh,
    float* __restrict__ stp, __bf16* __restrict__ wencT,
    __bf16* __restrict__ xbf, __bf16* __restrict__ stbf,
    __bf16* __restrict__ wihbf, __bf16* __restrict__ whhbf,
    float* __restrict__ scores)
{
    __shared__ float srow[512];
    int blk = blockIdx.x, tid = threadIdx.x;

    if (blk < 64) {
        int b = blk;
        srow[tid] = states[b * 512 + tid];
        srow[tid + 256] = states[b * 512 + tid + 256];
        __syncthreads();
        int n0 = tid, n1 = tid + 256;
        float a0 = 0.f, a1 = 0.f;
        for (int k = 0; k < 512; ++k) {
            float s = srow[k];
            a0 += s * W_state[k * 512 + n0];
            a1 += s * W_state[k * 512 + n1];
        }
        stp[b * 512 + n0] = a0;
        stp[b * 512 + n1] = a1;
    } else if (blk < 72) {
        int n = (blk - 64) * 64 + (tid & 63);
        int cseg = tid >> 6;
        for (int c = cseg * 16; c < cseg * 16 + 16; ++c) {
            f32x8 f;
            #pragma unroll
            for (int j = 0; j < 8; ++j) f[j] = W_enc[(c * 8 + j) * 512 + n];
            *(bf16x8*)(wencT + n * 512 + c * 8) = __builtin_convertvector(f, bf16x8);
        }
    } else if (blk < 840) {
        int base4 = (blk - 72) * 512 + tid * 2;
        #pragma unroll
        for (int j = 0; j < 2; ++j) {
            int i4 = base4 + j;
            f32x4 f = *(const f32x4*)(W_ih + i4 * 4);
            *(bf16x4*)(wihbf + i4 * 4) = __builtin_convertvector(f, bf16x4);
        }
    } else if (blk < 1224) {
        int base4 = (blk - 840) * 512 + tid * 2;
        #pragma unroll
        for (int j = 0; j < 2; ++j) {
            int i4 = base4 + j;
            f32x4 f = *(const f32x4*)(W_hh + i4 * 4);
            *(bf16x4*)(whhbf + i4 * 4) = __builtin_convertvector(f, bf16x4);
        }
    } else if (blk < 1240) {
        int base4 = (blk - 1224) * 512 + tid * 2;
        #pragma unroll
        for (int j = 0; j < 2; ++j) {
            int i4 = base4 + j;
            int e = i4 * 4;
            int b = e >> 9, c = e & 511;
            f32x4 f = *(const f32x4*)(inputs + e);
            *(bf16x4*)(xbf + b * 1024 + c) = __builtin_convertvector(f, bf16x4);
        }
    } else if (blk < 1256) {
        int base4 = (blk - 1240) * 512 + tid * 2;
        #pragma unroll
        for (int j = 0; j < 2; ++j) {
            int i4 = base4 + j;
            int e = i4 * 4;
            f32x4 f = *(const f32x4*)(states + e);
            *(bf16x4*)(stbf + e) = __builtin_convertvector(f, bf16x4);
        }
    } else {
        int e = (blk - 1256) * 1024 + tid * 4;
        *(f32x4*)(scores + e) = (f32x4){0.f, 0.f, 0.f, 0.f};
    }
}

// ---------------------------------------------------------------------------
// score v3: 256x256 block tile, 2 col-halves per row-tile (atomicAdd merge).
// 8 waves (2 wrow x 4 wcol), wave tile 128x64, K-step 64, 64 MFMA per wave
// per barrier. Double-buffered LDS [256][72] bf16 (144B rows -> conflict-free
// b128). T14 reg-staging (issue-early/write-late), raw s_barrier + lgkmcnt
// only (prefetch loads stay in flight across barriers), T5 setprio, T1 XCD
// swizzle. Fused tanh + v-dot epilogue -> atomicAdd into scores.
// ---------------------------------------------------------------------------
__global__ __launch_bounds__(512, 2) void score_kernel(
    const float* __restrict__ enc, const __bf16* __restrict__ wencT,
    const float* __restrict__ stp, const float* __restrict__ v,
    float* __restrict__ scores)
{
    extern __shared__ char smem[];
    // A buffers at 0, 36864; B buffers at 73728, 110592 (each [256][72] bf16)
    int tid = threadIdx.x;
    int bid = blockIdx.x;
    int tile = (bid & 7) * 64 + (bid >> 3);        // XCD swizzle (512 % 8 == 0)
    int rt = tile >> 1, ch = tile & 1;
    int grow0 = rt * 256;                           // global row (b*1024 + t)
    int c0 = ch * 256;                              // col-half offset
    int b = grow0 >> 10;

    int lane = tid & 63, wid = tid >> 6;
    int wrow = wid >> 2, wcol = wid & 3;            // 2 x 4 waves
    int l15 = lane & 15, g = lane >> 4;

    f32x4 acc[8][4];
    #pragma unroll
    for (int m = 0; m < 8; ++m)
        #pragma unroll
        for (int n = 0; n < 4; ++n) acc[m][n] = (f32x4){0.f, 0.f, 0.f, 0.f};

    f32x4 aP[8];
    uint4v bP[4];

    auto stage_load = [&](int ks) {
        #pragma unroll
        for (int i = 0; i < 4; ++i) {
            int c = tid + i * 512;
            int row = c >> 3, s = c & 7;
            const float* p = enc + (size_t)(grow0 + row) * 512 + ks * 64 + s * 8;
            aP[i * 2]     = *(const f32x4*)(p);
            aP[i * 2 + 1] = *(const f32x4*)(p + 4);
        }
        #pragma unroll
        for (int i = 0; i < 4; ++i) {
            int c = tid + i * 512;
            int row = c >> 3, s = c & 7;
            bP[i] = *(const uint4v*)(wencT + (size_t)(c0 + row) * 512 + ks * 64 + s * 8);
        }
    };
    auto stage_write = [&](char* abuf, char* bbuf) {
        #pragma unroll
        for (int i = 0; i < 4; ++i) {
            int c = tid + i * 512;
            int row = c >> 3, s = c & 7;
            f32x8 f;
            #pragma unroll
            for (int j = 0; j < 4; ++j) { f[j] = aP[i * 2][j]; f[4 + j] = aP[i * 2 + 1][j]; }
            *(bf16x8*)(abuf + row * 144 + s * 16) = __builtin_convertvector(f, bf16x8);
        }
        #pragma unroll
        for (int i = 0; i < 4; ++i) {
            int c = tid + i * 512;
            int row = c >> 3, s = c & 7;
            *(uint4v*)(bbuf + row * 144 + s * 16) = bP[i];
        }
    };

    // prologue: stage ks=0 into buf0, issue loads for ks=1
    stage_load(0);
    stage_write(smem, smem + 73728);
    stage_load(1);
    asm volatile("s_waitcnt lgkmcnt(0)" ::: "memory");
    __builtin_amdgcn_s_barrier();

    int cur = 0;
    for (int ks = 0; ks < 8; ++ks) {
        const char* Acur = smem + cur * 36864;
        const char* Bcur = smem + 73728 + cur * 36864;
        #pragma unroll
        for (int ksub = 0; ksub < 2; ++ksub) {
            bf16x8 af[8], bfr[4];
            #pragma unroll
            for (int m = 0; m < 8; ++m)
                af[m] = *(const bf16x8*)(Acur + (wrow * 128 + m * 16 + l15) * 144 + ksub * 64 + g * 16);
            #pragma unroll
            for (int n = 0; n < 4; ++n)
                bfr[n] = *(const bf16x8*)(Bcur + (wcol * 64 + n * 16 + l15) * 144 + ksub * 64 + g * 16);
            __builtin_amdgcn_s_setprio(1);
            #pragma unroll
            for (int m = 0; m < 8; ++m)
                #pragma unroll
                for (int n = 0; n < 4; ++n)
                    acc[m][n] = __builtin_amdgcn_mfma_f32_16x16x32_bf16(
                        af[m], bfr[n], acc[m][n], 0, 0, 0);
            __builtin_amdgcn_s_setprio(0);
        }
        if (ks < 7) {
            // write-late: convert ks+1 regs (implicit vmcnt wait here), write
            // to the other buffer, then issue loads for ks+2 (stay in flight
            // across the barrier).
            char* Anew = smem + (cur ^ 1) * 36864;
            char* Bnew = smem + 73728 + (cur ^ 1) * 36864;
            stage_write(Anew, Bnew);
            if (ks < 6) stage_load(ks + 2);
            asm volatile("s_waitcnt lgkmcnt(0)" ::: "memory");
            __builtin_amdgcn_s_barrier();
            cur ^= 1;
        }
    }

    // fused epilogue: score_row += v[col] * tanh(proj + st_proj[col])
    float sv[4], vw[4];
    #pragma unroll
    for (int n = 0; n < 4; ++n) {
        int col = c0 + wcol * 64 + n * 16 + l15;
        sv[n] = stp[b * 512 + col];
        vw[n] = v[col];
    }
    float rp[32];
    #pragma unroll
    for (int i = 0; i < 32; ++i) rp[i] = 0.f;
    #pragma unroll
    for (int m = 0; m < 8; ++m)
        #pragma unroll
        for (int n = 0; n < 4; ++n) {
            #pragma unroll
            for (int r = 0; r < 4; ++r)
                rp[m * 4 + r] += vw[n] * fast_tanh(acc[m][n][r] + sv[n]);
        }
    #pragma unroll
    for (int i = 0; i < 32; ++i) {
        rp[i] += __shfl_xor(rp[i], 1);
        rp[i] += __shfl_xor(rp[i], 2);
        rp[i] += __shfl_xor(rp[i], 4);
        rp[i] += __shfl_xor(rp[i], 8);
    }
    // sacc region (4 KB) at smem+0 = A buf0; last compute read buf1 -> safe.
    float* sacc = (float*)smem;
    if (l15 == 0) {
        #pragma unroll
        for (int m = 0; m < 8; ++m)
            #pragma unroll
            for (int r = 0; r < 4; ++r)
                sacc[wcol * 256 + wrow * 128 + m * 16 + g * 4 + r] = rp[m * 4 + r];
    }
    __syncthreads();
    if (tid < 256) {
        float val = sacc[tid] + sacc[256 + tid] + sacc[512 + tid] + sacc[768 + tid];
        atomicAdd(scores + grow0 + tid, val);
    }
}

// ---------------------------------------------------------------------------
// ctx (unchanged): softmax + context, writes bf16 context half of x.
// ---------------------------------------------------------------------------
__global__ __launch_bounds__(256) void ctx_kernel(
    const float* __restrict__ scores, const float* __restrict__ enc,
    __bf16* __restrict__ xbf)
{
    __shared__ float wsm[1024];
    __shared__ float red[512];
    __shared__ float tmp[8];
    int tid = threadIdx.x, lane = tid & 63, w = tid >> 6;
    int b = blockIdx.x >> 2, c0 = (blockIdx.x & 3) * 128;

    f32x4 s = *(const f32x4*)(scores + b * 1024 + tid * 4);
    float m = fmaxf(fmaxf(s[0], s[1]), fmaxf(s[2], s[3]));
    #pragma unroll
    for (int off = 32; off >= 1; off >>= 1) m = fmaxf(m, __shfl_xor(m, off));
    if (lane == 0) tmp[w] = m;
    __syncthreads();
    float M = fmaxf(fmaxf(tmp[0], tmp[1]), fmaxf(tmp[2], tmp[3]));
    float e0 = __expf(s[0] - M), e1 = __expf(s[1] - M);
    float e2 = __expf(s[2] - M), e3 = __expf(s[3] - M);
    wsm[tid * 4 + 0] = e0; wsm[tid * 4 + 1] = e1;
    wsm[tid * 4 + 2] = e2; wsm[tid * 4 + 3] = e3;
    float sum = e0 + e1 + e2 + e3;
    #pragma unroll
    for (int off = 32; off >= 1; off >>= 1) sum += __shfl_xor(sum, off);
    if (lane == 0) tmp[4 + w] = sum;
    __syncthreads();
    float S = tmp[4] + tmp[5] + tmp[6] + tmp[7];

    const float* ep = enc + ((b * 1024 + w * 256) * 512 + c0 + lane * 2);
    float ax = 0.f, ay = 0.f;
    #pragma unroll 4
    for (int t = 0; t < 256; ++t) {
        float wt = wsm[w * 256 + t];
        float2 ev = *(const float2*)(ep + t * 512);
        ax += wt * ev.x;
        ay += wt * ev.y;
    }
    red[w * 128 + lane * 2] = ax;
    red[w * 128 + lane * 2 + 1] = ay;
    __syncthreads();
    if (tid < 128) {
        float c = (red[tid] + red[128 + tid] + red[256 + tid] + red[384 + tid]) / S;
        xbf[b * 1024 + 512 + c0 + tid] = (__bf16)c;
    }
}

// ---------------------------------------------------------------------------
// gru_gemm (unchanged)
// ---------------------------------------------------------------------------
__global__ __launch_bounds__(256) void gru_gemm(
    const __bf16* __restrict__ xbf, const __bf16* __restrict__ stbf,
    const __bf16* __restrict__ wihbf, const __bf16* __restrict__ whhbf,
    const float* __restrict__ b_ih, const float* __restrict__ b_hh,
    float* __restrict__ gi, float* __restrict__ gh)
{
    __shared__ __align__(16) __bf16 As[64 * 72];
    __shared__ __align__(16) __bf16 Bs[128 * 72];
    int blk = blockIdx.x, tid = threadIdx.x;
    bool is_gh = blk >= 12;
    int n0 = (is_gh ? blk - 12 : blk) * 128;
    int K = is_gh ? 512 : 1024;
    const __bf16* Aptr = is_gh ? stbf : xbf;
    const __bf16* Bptr = is_gh ? whhbf : wihbf;
    const float* bias = is_gh ? b_hh : b_ih;
    float* outp = is_gh ? gh : gi;

    int lane = tid & 63, wid = tid >> 6, l15 = lane & 15, g = lane >> 4;
    f32x4 acc[4][2];
    #pragma unroll
    for (int i = 0; i < 4; ++i)
        #pragma unroll
        for (int j = 0; j < 2; ++j) acc[i][j] = (f32x4){0.f, 0.f, 0.f, 0.f};

    int nkc = K >> 6;
    for (int kc = 0; kc < nkc; ++kc) {
        int k0 = kc * 64;
        #pragma unroll
        for (int q = 0; q < 2; ++q) {
            int ch = tid * 2 + q, row = ch >> 3, seg = ch & 7;
            uint4v u = *(const uint4v*)(Aptr + row * K + k0 + seg * 8);
            *(uint4v*)(As + row * 72 + seg * 8) = u;
        }
        #pragma unroll
        for (int q = 0; q < 4; ++q) {
            int ch = tid * 4 + q, row = ch >> 3, seg = ch & 7;
            uint4v u = *(const uint4v*)(Bptr + (n0 + row) * K + k0 + seg * 8);
            *(uint4v*)(Bs + row * 72 + seg * 8) = u;
        }
        __syncthreads();
        #pragma unroll
        for (int kk = 0; kk < 2; ++kk) {
            bf16x8 af[4], bfr[2];
            #pragma unroll
            for (int m = 0; m < 4; ++m)
                af[m] = *(const bf16x8*)(As + (m * 16 + l15) * 72 + kk * 32 + g * 8);
            #pragma unroll
            for (int n = 0; n < 2; ++n)
                bfr[n] = *(const bf16x8*)(Bs + (wid * 32 + n * 16 + l15) * 72 + kk * 32 + g * 8);
            #pragma unroll
            for (int m = 0; m < 4; ++m)
                #pragma unroll
                for (int n = 0; n < 2; ++n)
                    acc[m][n] = __builtin_amdgcn_mfma_f32_16x16x32_bf16(
                        af[m], bfr[n], acc[m][n], 0, 0, 0);
        }
        __syncthreads();
    }
    #pragma unroll
    for (int m = 0; m < 4; ++m)
        #pragma unroll
        for (int n = 0; n < 2; ++n) {
            int col = n0 + wid * 32 + n * 16 + l15;
            float bb = bias[col];
            #pragma unroll
            for (int r = 0; r < 4; ++r) {
                int brow = m * 16 + g * 4 + r;
                outp[brow * 1536 + col] = acc[m][n][r] + bb;
            }
        }
}

// ---------------------------------------------------------------------------
// gates (unchanged)
// ---------------------------------------------------------------------------
__global__ __launch_bounds__(256) void gru_gates(
    const float* __restrict__ gi, const float* __restrict__ gh,
    const float* __restrict__ states, float* __restrict__ out)
{
    int i = blockIdx.x * 256 + threadIdx.x;  // 32768 total
    int b = i >> 9, j = i & 511;
    const float* gib = gi + b * 1536;
    const float* ghb = gh + b * 1536;
    float r = fast_sigmoid(gib[j] + ghb[j]);
    float z = fast_sigmoid(gib[512 + j] + ghb[512 + j]);
    float n = fast_tanh(gib[1024 + j] + r * ghb[1024 + j]);
    out[i] = (1.f - z) * n + z * states[i];
}

// ---------------------------------------------------------------------------
extern "C" void kernel_launch(void* const* d_in, const int* in_sizes, int n_in,
                              void* d_out, int out_size, void* d_ws, size_t ws_size,
                              hipStream_t stream)
{
    const float* inputs  = (const float*)d_in[0];
    const float* states  = (const float*)d_in[1];
    const float* encoded = (const float*)d_in[2];
    const float* W_enc   = (const float*)d_in[3];
    const float* W_state = (const float*)d_in[4];
    const float* v       = (const float*)d_in[5];
    const float* W_ih    = (const float*)d_in[6];
    const float* W_hh    = (const float*)d_in[7];
    const float* b_ih    = (const float*)d_in[8];
    const float* b_hh    = (const float*)d_in[9];
    float* out = (float*)d_out;
    char* ws = (char*)d_ws;

    float*  stp    = (float*)(ws + 0);         //  64*512*4   = 131072
    __bf16* wencT  = (__bf16*)(ws + 131072);   // 512*512*2   = 524288
    float*  scores = (float*)(ws + 655360);    //  64*1024*4  = 262144
    __bf16* xbf    = (__bf16*)(ws + 917504);   //  64*1024*2  = 131072
    __bf16* stbf   = (__bf16*)(ws + 1048576);  //  64*512*2   = 65536
    __bf16* wihbf  = (__bf16*)(ws + 1114112);  // 1536*1024*2 = 3145728
    __bf16* whhbf  = (__bf16*)(ws + 4259840);  // 1536*512*2  = 1572864
    float*  gi     = (float*)(ws + 5832704);   //  64*1536*4  = 393216
    float*  gh     = (float*)(ws + 6225920);   //  64*1536*4  = 393216

    prep_kernel<<<1320, 256, 0, stream>>>(states, W_enc, W_state, inputs, W_ih, W_hh,
                                          stp, wencT, xbf, stbf, wihbf, whhbf, scores);
    score_kernel<<<512, 512, 147456, stream>>>(encoded, wencT, stp, v, scores);
    ctx_kernel<<<256, 256, 0, stream>>>(scores, encoded, xbf);
    gru_gemm<<<24, 256, 0, stream>>>(xbf, stbf, wihbf, whhbf, b_ih, b_hh, gi, gh);
    gru_gates<<<128, 256, 0, stream>>>(gi, gh, states, out);
}